// Round 4
// baseline (448.572 us; speedup 1.0000x reference)
//
#include <hip/hip_runtime.h>
#include <math.h>

#define NF 64

// ---------------------------------------------------------------------------
// CSR build: histogram of dst
// ---------------------------------------------------------------------------
__global__ __launch_bounds__(256) void k_hist(
    const int* __restrict__ ei, int* __restrict__ deg, int E) {
    int e = blockIdx.x * 256 + threadIdx.x;
    if (e < E) atomicAdd(&deg[ei[E + e]], 1);
}

// ---------------------------------------------------------------------------
// Exclusive scan, 3 kernels (N <= 512*256)
// ---------------------------------------------------------------------------
__global__ __launch_bounds__(256) void k_scan1(
    const int* __restrict__ deg, int* __restrict__ base,
    int* __restrict__ bsums, int N) {
    __shared__ int s[256];
    int t = threadIdx.x, i = blockIdx.x * 256 + t;
    int v = (i < N) ? deg[i] : 0;
    s[t] = v;
    __syncthreads();
    for (int off = 1; off < 256; off <<= 1) {
        int add = (t >= off) ? s[t - off] : 0;
        __syncthreads();
        s[t] += add;
        __syncthreads();
    }
    if (i < N) base[i] = s[t] - v;           // exclusive within block
    if (t == 255) bsums[blockIdx.x] = s[255];
}

__global__ __launch_bounds__(512) void k_scan2(
    int* __restrict__ bsums, int nb) {
    __shared__ int s[512];
    int t = threadIdx.x;
    int v = (t < nb) ? bsums[t] : 0;
    s[t] = v;
    __syncthreads();
    for (int off = 1; off < 512; off <<= 1) {
        int add = (t >= off) ? s[t - off] : 0;
        __syncthreads();
        s[t] += add;
        __syncthreads();
    }
    if (t < nb) bsums[t] = s[t] - v;         // exclusive
}

__global__ __launch_bounds__(256) void k_scan3(
    int* __restrict__ base, const int* __restrict__ bsums, int N) {
    int i = blockIdx.x * 256 + threadIdx.x;
    if (i < N) base[i] += bsums[blockIdx.x];
}

// ---------------------------------------------------------------------------
// Counting-sort src by dst segment (order within segment irrelevant for sum)
// ---------------------------------------------------------------------------
__global__ __launch_bounds__(256) void k_build(
    const int* __restrict__ ei, const int* __restrict__ base,
    int* __restrict__ cursor, int* __restrict__ sorted, int E) {
    int e = blockIdx.x * 256 + threadIdx.x;
    if (e >= E) return;
    int s = ei[e];
    int d = ei[E + e];
    int pos = atomicAdd(&cursor[d], 1);
    sorted[base[d] + pos] = s;
}

// ---------------------------------------------------------------------------
// Gather-sum x rows over CSR -> mean. One wave per node (grid-stride).
// Neighbor indices are wave-uniform: readfirstlane forces scalar loads
// (no ds_bpermute), unroll x8 keeps 8 independent 256B row loads in flight.
// Minimal VGPR use -> high occupancy for latency hiding.
// ---------------------------------------------------------------------------
__global__ __launch_bounds__(256) void k_gather(
    const float* __restrict__ x,
    const int* __restrict__ sorted,
    const int* __restrict__ base,
    const int* __restrict__ deg,
    float* __restrict__ mean,
    int N, int nwaves) {
    int tid = blockIdx.x * 256 + threadIdx.x;
    int gw = tid >> 6;
    int lane = tid & 63;

    for (int node = gw; node < N; node += nwaves) {
        int b0 = __builtin_amdgcn_readfirstlane(base[node]);
        int dg = __builtin_amdgcn_readfirstlane(deg[node]);

        float sum = 0.f;
        int j = 0;
        for (; j + 8 <= dg; j += 8) {
            int i0 = __builtin_amdgcn_readfirstlane(sorted[b0 + j + 0]);
            int i1 = __builtin_amdgcn_readfirstlane(sorted[b0 + j + 1]);
            int i2 = __builtin_amdgcn_readfirstlane(sorted[b0 + j + 2]);
            int i3 = __builtin_amdgcn_readfirstlane(sorted[b0 + j + 3]);
            int i4 = __builtin_amdgcn_readfirstlane(sorted[b0 + j + 4]);
            int i5 = __builtin_amdgcn_readfirstlane(sorted[b0 + j + 5]);
            int i6 = __builtin_amdgcn_readfirstlane(sorted[b0 + j + 6]);
            int i7 = __builtin_amdgcn_readfirstlane(sorted[b0 + j + 7]);
            float v0 = x[(size_t)i0 * NF + lane];
            float v1 = x[(size_t)i1 * NF + lane];
            float v2 = x[(size_t)i2 * NF + lane];
            float v3 = x[(size_t)i3 * NF + lane];
            float v4 = x[(size_t)i4 * NF + lane];
            float v5 = x[(size_t)i5 * NF + lane];
            float v6 = x[(size_t)i6 * NF + lane];
            float v7 = x[(size_t)i7 * NF + lane];
            sum += ((v0 + v1) + (v2 + v3)) + ((v4 + v5) + (v6 + v7));
        }
        for (; j < dg; ++j) {
            int i0 = __builtin_amdgcn_readfirstlane(sorted[b0 + j]);
            sum += x[(size_t)i0 * NF + lane];
        }
        float dgf = (float)(dg > 1 ? dg : 1);
        mean[(size_t)node * NF + lane] = sum / dgf;
    }
}

// ---------------------------------------------------------------------------
// Dense transform: h = mean@Wl1^T + bl1 + x@Wr1^T; emit p = h@Wl2^T,
// q = h@Wr2^T. One wave per node (grid-stride); weights loaded ONCE per
// wave before the loop (goal: VGPR-resident; check VGPR_Count in profile).
// ---------------------------------------------------------------------------
__global__ void k_dense(
    const float* __restrict__ x,
    const float* __restrict__ mean,
    const float* __restrict__ Wl1,
    const float* __restrict__ bl1,
    const float* __restrict__ Wr1,
    const float* __restrict__ Wl2,
    const float* __restrict__ Wr2,
    float2* __restrict__ p,
    float2* __restrict__ q,
    int N, int nwaves) {
    int tid = blockIdx.x * 256 + threadIdx.x;
    int gw = tid >> 6;
    int lane = tid & 63;

    // Lane o holds row o of Wl1 / Wr1 (contiguous 256 B per lane).
    float wl[NF], wr[NF];
    {
        const float4* wl4 = (const float4*)(Wl1 + (size_t)lane * NF);
        const float4* wr4 = (const float4*)(Wr1 + (size_t)lane * NF);
#pragma unroll
        for (int i = 0; i < NF / 4; ++i) {
            float4 a = wl4[i], b = wr4[i];
            wl[4 * i] = a.x; wl[4 * i + 1] = a.y; wl[4 * i + 2] = a.z; wl[4 * i + 3] = a.w;
            wr[4 * i] = b.x; wr[4 * i + 1] = b.y; wr[4 * i + 2] = b.z; wr[4 * i + 3] = b.w;
        }
    }
    float bl = bl1[lane];
    float wl2a = Wl2[lane], wl2b = Wl2[NF + lane];
    float wr2a = Wr2[lane], wr2b = Wr2[NF + lane];

    for (int node = gw; node < N; node += nwaves) {
        float mn = mean[(size_t)node * NF + lane];
        float xv = x[(size_t)node * NF + lane];

        float acc = bl;
#pragma unroll
        for (int k = 0; k < NF; ++k) {
            float mk = __uint_as_float(__builtin_amdgcn_readlane(__float_as_uint(mn), k));
            float xk = __uint_as_float(__builtin_amdgcn_readlane(__float_as_uint(xv), k));
            acc = fmaf(mk, wl[k], acc);
            acc = fmaf(xk, wr[k], acc);
        }

        float p0 = acc * wl2a, p1 = acc * wl2b;
        float q0 = acc * wr2a, q1 = acc * wr2b;
#pragma unroll
        for (int off = 32; off > 0; off >>= 1) {
            p0 += __shfl_xor(p0, off, 64);
            p1 += __shfl_xor(p1, off, 64);
            q0 += __shfl_xor(q0, off, 64);
            q1 += __shfl_xor(q1, off, 64);
        }
        if (lane == 0) {
            p[node] = make_float2(p0, p1);
            q[node] = make_float2(q0, q1);
        }
    }
}

// ---------------------------------------------------------------------------
// Final: agg2 = gather-sum p over CSR; logits = agg2/deg + bl2 + q;
// out = log_softmax(logits). One wave per node.
// ---------------------------------------------------------------------------
__global__ __launch_bounds__(256) void k_final(
    const float2* __restrict__ p,
    const float2* __restrict__ q,
    const int* __restrict__ sorted,
    const int* __restrict__ base,
    const int* __restrict__ deg,
    const float* __restrict__ bl2,
    float* __restrict__ out,
    int N) {
    int tid = blockIdx.x * 256 + threadIdx.x;
    int node = tid >> 6;
    int lane = tid & 63;
    if (node >= N) return;
    int b0 = base[node];
    int dg = deg[node];
    float s0 = 0.f, s1 = 0.f;
    for (int j = lane; j < dg; j += 64) {
        int idx = sorted[b0 + j];
        float2 pv = p[idx];
        s0 += pv.x; s1 += pv.y;
    }
#pragma unroll
    for (int off = 32; off > 0; off >>= 1) {
        s0 += __shfl_xor(s0, off, 64);
        s1 += __shfl_xor(s1, off, 64);
    }
    if (lane == 0) {
        float dgf = (float)(dg > 1 ? dg : 1);
        float2 qv = q[node];
        float l0 = s0 / dgf + bl2[0] + qv.x;
        float l1 = s1 / dgf + bl2[1] + qv.y;
        float m = fmaxf(l0, l1);
        float lse = m + logf(expf(l0 - m) + expf(l1 - m));
        ((float2*)out)[node] = make_float2(l0 - lse, l1 - lse);
    }
}

// ---------------------------------------------------------------------------
extern "C" void kernel_launch(void* const* d_in, const int* in_sizes, int n_in,
                              void* d_out, int out_size, void* d_ws, size_t ws_size,
                              hipStream_t stream) {
    const float* x   = (const float*)d_in[0];
    const int*   ei  = (const int*)d_in[1];
    const float* Wl1 = (const float*)d_in[2];
    const float* bl1 = (const float*)d_in[3];
    const float* Wr1 = (const float*)d_in[4];
    const float* Wl2 = (const float*)d_in[5];
    const float* bl2 = (const float*)d_in[6];
    const float* Wr2 = (const float*)d_in[7];
    float* out = (float*)d_out;

    int N = in_sizes[0] / NF;     // 100000
    int E = in_sizes[1] / 2;      // 1600000

    // Workspace:
    // ints:   [deg:N | cursor:N | base:N | bsums:512 | sorted:E]
    // floats: [p:2N | q:2N | mean:64N]   (~35 MB total)
    int* wsi    = (int*)d_ws;
    int* deg    = wsi;
    int* cursor = wsi + N;
    int* base   = wsi + 2 * (size_t)N;
    int* bsums  = wsi + 3 * (size_t)N;
    int* sorted = wsi + 3 * (size_t)N + 512;
    float2* p   = (float2*)(wsi + 3 * (size_t)N + 512 + E);
    float2* q   = p + N;
    float* mean = (float*)(q + N);

    // Zero deg + cursor (everything else fully overwritten).
    hipMemsetAsync(d_ws, 0, 2 * (size_t)N * sizeof(int), stream);

    int nbE = (E + 255) / 256;
    int nbN = (N + 255) / 256;

    k_hist <<<nbE, 256, 0, stream>>>(ei, deg, E);
    k_scan1<<<nbN, 256, 0, stream>>>(deg, base, bsums, N);
    k_scan2<<<1, 512, 0, stream>>>(bsums, nbN);
    k_scan3<<<nbN, 256, 0, stream>>>(base, bsums, N);
    k_build<<<nbE, 256, 0, stream>>>(ei, base, cursor, sorted, E);

    int gblocks = 4096;                        // 16384 waves, grid-stride
    k_gather<<<gblocks, 256, 0, stream>>>(x, sorted, base, deg, mean,
                                          N, gblocks * 4);
    int dblocks = 1024;                        // 4096 waves, VALU-bound
    k_dense<<<dblocks, 256, 0, stream>>>(x, mean, Wl1, bl1, Wr1, Wl2, Wr2,
                                         p, q, N, dblocks * 4);
    k_final<<<(N * 64 + 255) / 256, 256, 0, stream>>>(p, q, sorted, base, deg,
                                                      bl2, out, N);
}

// Round 5
// 341.121 us; speedup vs baseline: 1.3150x; 1.3150x over previous
//
#include <hip/hip_runtime.h>
#include <math.h>

#define NF 64

// ---------------------------------------------------------------------------
// CSR build: histogram of dst
// ---------------------------------------------------------------------------
__global__ __launch_bounds__(256) void k_hist(
    const int* __restrict__ ei, int* __restrict__ deg, int E) {
    int e = blockIdx.x * 256 + threadIdx.x;
    if (e < E) atomicAdd(&deg[ei[E + e]], 1);
}

// ---------------------------------------------------------------------------
// Exclusive scan, 3 kernels (N <= 512*256)
// ---------------------------------------------------------------------------
__global__ __launch_bounds__(256) void k_scan1(
    const int* __restrict__ deg, int* __restrict__ base,
    int* __restrict__ bsums, int N) {
    __shared__ int s[256];
    int t = threadIdx.x, i = blockIdx.x * 256 + t;
    int v = (i < N) ? deg[i] : 0;
    s[t] = v;
    __syncthreads();
    for (int off = 1; off < 256; off <<= 1) {
        int add = (t >= off) ? s[t - off] : 0;
        __syncthreads();
        s[t] += add;
        __syncthreads();
    }
    if (i < N) base[i] = s[t] - v;           // exclusive within block
    if (t == 255) bsums[blockIdx.x] = s[255];
}

__global__ __launch_bounds__(512) void k_scan2(
    int* __restrict__ bsums, int nb) {
    __shared__ int s[512];
    int t = threadIdx.x;
    int v = (t < nb) ? bsums[t] : 0;
    s[t] = v;
    __syncthreads();
    for (int off = 1; off < 512; off <<= 1) {
        int add = (t >= off) ? s[t - off] : 0;
        __syncthreads();
        s[t] += add;
        __syncthreads();
    }
    if (t < nb) bsums[t] = s[t] - v;         // exclusive
}

__global__ __launch_bounds__(256) void k_scan3(
    int* __restrict__ base, const int* __restrict__ bsums, int N) {
    int i = blockIdx.x * 256 + threadIdx.x;
    if (i < N) base[i] += bsums[blockIdx.x];
}

// ---------------------------------------------------------------------------
// Counting-sort src by dst segment (order within segment irrelevant for sum)
// ---------------------------------------------------------------------------
__global__ __launch_bounds__(256) void k_build(
    const int* __restrict__ ei, const int* __restrict__ base,
    int* __restrict__ cursor, int* __restrict__ sorted, int E) {
    int e = blockIdx.x * 256 + threadIdx.x;
    if (e >= E) return;
    int s = ei[e];
    int d = ei[E + e];
    int pos = atomicAdd(&cursor[d], 1);
    sorted[base[d] + pos] = s;
}

// ---------------------------------------------------------------------------
// Composite-matrix precompute (the dense layer collapsed to 64x2 matrices):
//   Mp[k][c] = sum_o Wl2[c][o]*Wl1[o][k]   (p's mean-term)
//   Np[k][c] = sum_o Wl2[c][o]*Wr1[o][k]   (p's x-term)
//   Mq[k][c] = sum_o Wr2[c][o]*Wl1[o][k]   (q's mean-term)
//   Nq[k][c] = sum_o Wr2[c][o]*Wr1[o][k]   (q's x-term)
//   cpq = [bl1@Wl2^T, bl1@Wr2^T]           (4 consts)
// comp layout (float2-per-k): [Mp:64 | Np:64 | Mq:64 | Nq:64] then 4 floats.
// One block, 256 threads; 64 MACs/thread.
// ---------------------------------------------------------------------------
__global__ __launch_bounds__(256) void k_compose(
    const float* __restrict__ Wl1, const float* __restrict__ bl1,
    const float* __restrict__ Wr1, const float* __restrict__ Wl2,
    const float* __restrict__ Wr2, float* __restrict__ comp) {
    int t = threadIdx.x;
    int m = t >> 6;          // 0:Mp 1:Np 2:Mq 3:Nq
    int k = t & 63;
    const float* W1 = (m == 0 || m == 2) ? Wl1 : Wr1;
    const float* W2 = (m < 2) ? Wl2 : Wr2;
    float a0 = 0.f, a1 = 0.f;
    for (int o = 0; o < NF; ++o) {
        float w1 = W1[o * NF + k];
        a0 = fmaf(W2[o], w1, a0);
        a1 = fmaf(W2[NF + o], w1, a1);
    }
    comp[2 * t] = a0;
    comp[2 * t + 1] = a1;
    if (t < 4) {             // cpq[t]: 0,1 -> bl1@Wl2^T ; 2,3 -> bl1@Wr2^T
        const float* W2c = (t < 2) ? Wl2 : Wr2;
        int c = t & 1;
        float s = 0.f;
        for (int o = 0; o < NF; ++o) s = fmaf(bl1[o], W2c[c * NF + o], s);
        comp[512 + t] = s;
    }
}

// ---------------------------------------------------------------------------
// Gather-sum x rows over CSR, then the 8-FMA composite epilogue -> p,q.
// One wave per node (grid-stride). Neighbor indices wave-uniform ->
// readfirstlane forces scalar loads; unroll x8 for MLP. ~20 VGPRs.
// ---------------------------------------------------------------------------
__global__ __launch_bounds__(256) void k_gatherp(
    const float* __restrict__ x,
    const int* __restrict__ sorted,
    const int* __restrict__ base,
    const int* __restrict__ deg,
    const float* __restrict__ comp,
    float2* __restrict__ p,
    float2* __restrict__ q,
    int N, int nwaves) {
    int tid = blockIdx.x * 256 + threadIdx.x;
    int gw = tid >> 6;
    int lane = tid & 63;

    const float2* c2 = (const float2*)comp;
    float2 mp = c2[lane];             // Mp[lane]
    float2 np = c2[64 + lane];        // Np[lane]
    float2 mq = c2[128 + lane];       // Mq[lane]
    float2 nq = c2[192 + lane];       // Nq[lane]
    float cp0 = comp[512], cp1 = comp[513], cq0 = comp[514], cq1 = comp[515];

    for (int node = gw; node < N; node += nwaves) {
        int b0 = __builtin_amdgcn_readfirstlane(base[node]);
        int dg = __builtin_amdgcn_readfirstlane(deg[node]);

        float sum = 0.f;
        int j = 0;
        for (; j + 8 <= dg; j += 8) {
            int i0 = __builtin_amdgcn_readfirstlane(sorted[b0 + j + 0]);
            int i1 = __builtin_amdgcn_readfirstlane(sorted[b0 + j + 1]);
            int i2 = __builtin_amdgcn_readfirstlane(sorted[b0 + j + 2]);
            int i3 = __builtin_amdgcn_readfirstlane(sorted[b0 + j + 3]);
            int i4 = __builtin_amdgcn_readfirstlane(sorted[b0 + j + 4]);
            int i5 = __builtin_amdgcn_readfirstlane(sorted[b0 + j + 5]);
            int i6 = __builtin_amdgcn_readfirstlane(sorted[b0 + j + 6]);
            int i7 = __builtin_amdgcn_readfirstlane(sorted[b0 + j + 7]);
            float v0 = x[(size_t)i0 * NF + lane];
            float v1 = x[(size_t)i1 * NF + lane];
            float v2 = x[(size_t)i2 * NF + lane];
            float v3 = x[(size_t)i3 * NF + lane];
            float v4 = x[(size_t)i4 * NF + lane];
            float v5 = x[(size_t)i5 * NF + lane];
            float v6 = x[(size_t)i6 * NF + lane];
            float v7 = x[(size_t)i7 * NF + lane];
            sum += ((v0 + v1) + (v2 + v3)) + ((v4 + v5) + (v6 + v7));
        }
        for (; j < dg; ++j) {
            int i0 = __builtin_amdgcn_readfirstlane(sorted[b0 + j]);
            sum += x[(size_t)i0 * NF + lane];
        }
        float dgf = (float)(dg > 1 ? dg : 1);
        float mean = sum / dgf;                     // lane k holds mean[k]
        float xv = x[(size_t)node * NF + lane];     // lane k holds x[k]

        // 8 FMAs replace the whole 64x64x2 dense transform per node.
        float p0 = fmaf(mean, mp.x, xv * np.x);
        float p1 = fmaf(mean, mp.y, xv * np.y);
        float q0 = fmaf(mean, mq.x, xv * nq.x);
        float q1 = fmaf(mean, mq.y, xv * nq.y);
#pragma unroll
        for (int off = 32; off > 0; off >>= 1) {
            p0 += __shfl_xor(p0, off, 64);
            p1 += __shfl_xor(p1, off, 64);
            q0 += __shfl_xor(q0, off, 64);
            q1 += __shfl_xor(q1, off, 64);
        }
        if (lane == 0) {
            p[node] = make_float2(p0 + cp0, p1 + cp1);
            q[node] = make_float2(q0 + cq0, q1 + cq1);
        }
    }
}

// ---------------------------------------------------------------------------
// Final: agg2 = gather-sum p over CSR; logits = agg2/deg + bl2 + q;
// out = log_softmax(logits). One wave per node.
// ---------------------------------------------------------------------------
__global__ __launch_bounds__(256) void k_final(
    const float2* __restrict__ p,
    const float2* __restrict__ q,
    const int* __restrict__ sorted,
    const int* __restrict__ base,
    const int* __restrict__ deg,
    const float* __restrict__ bl2,
    float* __restrict__ out,
    int N) {
    int tid = blockIdx.x * 256 + threadIdx.x;
    int node = tid >> 6;
    int lane = tid & 63;
    if (node >= N) return;
    int b0 = base[node];
    int dg = deg[node];
    float s0 = 0.f, s1 = 0.f;
    for (int j = lane; j < dg; j += 64) {
        int idx = sorted[b0 + j];
        float2 pv = p[idx];
        s0 += pv.x; s1 += pv.y;
    }
#pragma unroll
    for (int off = 32; off > 0; off >>= 1) {
        s0 += __shfl_xor(s0, off, 64);
        s1 += __shfl_xor(s1, off, 64);
    }
    if (lane == 0) {
        float dgf = (float)(dg > 1 ? dg : 1);
        float2 qv = q[node];
        float l0 = s0 / dgf + bl2[0] + qv.x;
        float l1 = s1 / dgf + bl2[1] + qv.y;
        float m = fmaxf(l0, l1);
        float lse = m + logf(expf(l0 - m) + expf(l1 - m));
        ((float2*)out)[node] = make_float2(l0 - lse, l1 - lse);
    }
}

// ---------------------------------------------------------------------------
extern "C" void kernel_launch(void* const* d_in, const int* in_sizes, int n_in,
                              void* d_out, int out_size, void* d_ws, size_t ws_size,
                              hipStream_t stream) {
    const float* x   = (const float*)d_in[0];
    const int*   ei  = (const int*)d_in[1];
    const float* Wl1 = (const float*)d_in[2];
    const float* bl1 = (const float*)d_in[3];
    const float* Wr1 = (const float*)d_in[4];
    const float* Wl2 = (const float*)d_in[5];
    const float* bl2 = (const float*)d_in[6];
    const float* Wr2 = (const float*)d_in[7];
    float* out = (float*)d_out;

    int N = in_sizes[0] / NF;     // 100000
    int E = in_sizes[1] / 2;      // 1600000

    // Workspace:
    // ints:   [deg:N | cursor:N | base:N | bsums:512 | sorted:E]
    // floats: [p:2N | q:2N | comp:516]
    int* wsi    = (int*)d_ws;
    int* deg    = wsi;
    int* cursor = wsi + N;
    int* base   = wsi + 2 * (size_t)N;
    int* bsums  = wsi + 3 * (size_t)N;
    int* sorted = wsi + 3 * (size_t)N + 512;
    float2* p   = (float2*)(wsi + 3 * (size_t)N + 512 + E);
    float2* q   = p + N;
    float* comp = (float*)(q + N);

    // Zero deg + cursor (everything else fully overwritten).
    hipMemsetAsync(d_ws, 0, 2 * (size_t)N * sizeof(int), stream);

    int nbE = (E + 255) / 256;
    int nbN = (N + 255) / 256;

    k_hist <<<nbE, 256, 0, stream>>>(ei, deg, E);
    k_scan1<<<nbN, 256, 0, stream>>>(deg, base, bsums, N);
    k_scan2<<<1, 512, 0, stream>>>(bsums, nbN);
    k_scan3<<<nbN, 256, 0, stream>>>(base, bsums, N);
    k_build<<<nbE, 256, 0, stream>>>(ei, base, cursor, sorted, E);
    k_compose<<<1, 256, 0, stream>>>(Wl1, bl1, Wr1, Wl2, Wr2, comp);

    int gblocks = 4096;                        // 16384 waves, grid-stride
    k_gatherp<<<gblocks, 256, 0, stream>>>(x, sorted, base, deg, comp,
                                           p, q, N, gblocks * 4);
    k_final<<<(N * 64 + 255) / 256, 256, 0, stream>>>(p, q, sorted, base, deg,
                                                      bl2, out, N);
}

// Round 6
// 235.339 us; speedup vs baseline: 1.9061x; 1.4495x over previous
//
#include <hip/hip_runtime.h>
#include <math.h>

#define NF 64
#define SHIFT 9              // 512 nodes per dst-bucket
#define BSZ 512
#define MAXNB 256            // LDS arrays sized for <=256 buckets (N <= 131072)
#define CHUNK 4096           // edges per kb_bin block

// ---------------------------------------------------------------------------
// Bucket histogram of dst>>SHIFT (LDS-aggregated to cut global atomics).
// ---------------------------------------------------------------------------
__global__ __launch_bounds__(256) void kb_hist(
    const int* __restrict__ ei, int* __restrict__ bhist, int E, int nb) {
    __shared__ int h[MAXNB];
    int t = threadIdx.x;
    if (t < nb) h[t] = 0;
    __syncthreads();
    int stride = gridDim.x * 256;
    for (int e = blockIdx.x * 256 + t; e < E; e += stride)
        atomicAdd(&h[((unsigned)ei[E + e]) >> SHIFT], 1);
    __syncthreads();
    if (t < nb && h[t]) atomicAdd(&bhist[t], h[t]);
}

// ---------------------------------------------------------------------------
// Exclusive scan of bucket counts -> bbase (and a working copy bcur).
// ---------------------------------------------------------------------------
__global__ __launch_bounds__(256) void kb_scan(
    const int* __restrict__ bhist, int* __restrict__ bbase,
    int* __restrict__ bcur, int nb) {
    __shared__ int s[256];
    int t = threadIdx.x;
    int v = (t < nb) ? bhist[t] : 0;
    s[t] = v;
    __syncthreads();
    for (int off = 1; off < 256; off <<= 1) {
        int a = (t >= off) ? s[t - off] : 0;
        __syncthreads();
        s[t] += a;
        __syncthreads();
    }
    if (t < nb) { bbase[t] = s[t] - v; bcur[t] = s[t] - v; }
    if (t == nb - 1) bbase[nb] = s[t];      // total = E
}

// ---------------------------------------------------------------------------
// Binned scatter with in-LDS local sort: each block counting-sorts a 4096-edge
// chunk by bucket in LDS, then flushes each bucket's run as a CONTIGUOUS
// global write (kills the 16x line-bounce amplification of random scatter).
// Edge packed to 25 bits: (d_local<<17)|src  (requires N < 2^17).
// ---------------------------------------------------------------------------
__global__ __launch_bounds__(256) void kb_bin(
    const int* __restrict__ ei, int* __restrict__ bcur,
    int* __restrict__ ebin, int E, int nb) {
    __shared__ int spair[CHUNK];
    __shared__ unsigned short sbkt[CHUNK];
    __shared__ int h[MAXNB], sb[MAXNB], lcur[MAXNB], goff[MAXNB];
    __shared__ int ss[256];
    int t = threadIdx.x;
    int e0 = blockIdx.x * CHUNK;
    if (t < nb) h[t] = 0;
    __syncthreads();

    int pv[CHUNK / 256], pb[CHUNK / 256];
#pragma unroll
    for (int k = 0; k < CHUNK / 256; ++k) {
        int e = e0 + k * 256 + t;
        if (e < E) {
            int sv = ei[e];
            unsigned d = (unsigned)ei[E + e];
            int b = d >> SHIFT;
            pb[k] = b;
            pv[k] = (int)(((d & (BSZ - 1)) << 17) | (unsigned)sv);
            atomicAdd(&h[b], 1);
        } else pb[k] = -1;
    }
    __syncthreads();
    {   // exclusive scan h -> sb (and cursor copy)
        int v = (t < nb) ? h[t] : 0;
        ss[t] = v;
        __syncthreads();
        for (int off = 1; off < 256; off <<= 1) {
            int a = (t >= off) ? ss[t - off] : 0;
            __syncthreads();
            ss[t] += a;
            __syncthreads();
        }
        if (t < nb) { sb[t] = ss[t] - v; lcur[t] = ss[t] - v; }
    }
    __syncthreads();
#pragma unroll
    for (int k = 0; k < CHUNK / 256; ++k) {
        if (pb[k] >= 0) {
            int pos = atomicAdd(&lcur[pb[k]], 1);
            spair[pos] = pv[k];
            sbkt[pos] = (unsigned short)pb[k];
        }
    }
    __syncthreads();
    if (t < nb && h[t] > 0) goff[t] = atomicAdd(&bcur[t], h[t]);
    __syncthreads();
    int M = min(CHUNK, E - e0);
    for (int i = t; i < M; i += 256) {      // bucket runs -> contiguous writes
        int b = sbkt[i];
        ebin[goff[b] + i - sb[b]] = spair[i];
    }
}

// ---------------------------------------------------------------------------
// Per-bucket final counting sort: one block per bucket; scatter stays inside
// a ~32 KB region (one CU's L2). Also emits deg[] and base[] (CSR offsets),
// replacing the old k_hist + 3-kernel scan.
// ---------------------------------------------------------------------------
__global__ __launch_bounds__(512) void kb_sort(
    const int* __restrict__ ebin, const int* __restrict__ bbase,
    int* __restrict__ sorted, int* __restrict__ deg, int* __restrict__ base,
    int N, int nb) {
    __shared__ int h[BSZ], lb[BSZ], ss[BSZ];
    int b = blockIdx.x;
    int t = threadIdx.x;
    int gstart = bbase[b];
    int cnt = bbase[b + 1] - gstart;
    int n0 = b << SHIFT;
    int nn = min(BSZ, N - n0);
    h[t] = 0;
    __syncthreads();
    for (int i = t; i < cnt; i += 512)
        atomicAdd(&h[ebin[gstart + i] >> 17], 1);
    __syncthreads();
    int v = h[t];
    ss[t] = v;
    __syncthreads();
    for (int off = 1; off < 512; off <<= 1) {
        int a = (t >= off) ? ss[t - off] : 0;
        __syncthreads();
        ss[t] += a;
        __syncthreads();
    }
    lb[t] = ss[t] - v;                      // exclusive within bucket
    if (t < nn) { deg[n0 + t] = v; base[n0 + t] = gstart + lb[t]; }
    __syncthreads();
    h[t] = 0;                               // reuse as per-node cursor
    __syncthreads();
    for (int i = t; i < cnt; i += 512) {
        int pv = ebin[gstart + i];
        int dl = pv >> 17;
        int pos = atomicAdd(&h[dl], 1);
        sorted[gstart + lb[dl] + pos] = pv & 0x1FFFF;
    }
}

// ---------------------------------------------------------------------------
// Cast x to bf16 (RTN) -> xh. Gather reads then cost 128 B/row, not 256 B.
// ---------------------------------------------------------------------------
__global__ __launch_bounds__(256) void k_xcast(
    const float4* __restrict__ x4, ushort4* __restrict__ xh4, int n4) {
    int stride = gridDim.x * 256;
    for (int i = blockIdx.x * 256 + threadIdx.x; i < n4; i += stride) {
        float4 f = x4[i];
        ushort4 o;
        unsigned u;
        u = __float_as_uint(f.x); o.x = (unsigned short)((u + 0x7FFF + ((u >> 16) & 1)) >> 16);
        u = __float_as_uint(f.y); o.y = (unsigned short)((u + 0x7FFF + ((u >> 16) & 1)) >> 16);
        u = __float_as_uint(f.z); o.z = (unsigned short)((u + 0x7FFF + ((u >> 16) & 1)) >> 16);
        u = __float_as_uint(f.w); o.w = (unsigned short)((u + 0x7FFF + ((u >> 16) & 1)) >> 16);
        xh4[i] = o;
    }
}

// ---------------------------------------------------------------------------
// Composite-matrix precompute (dense layers collapsed to 64x2):
// comp layout (float2-per-k): [Mp:64 | Np:64 | Mq:64 | Nq:64] then 4 floats.
// ---------------------------------------------------------------------------
__global__ __launch_bounds__(256) void k_compose(
    const float* __restrict__ Wl1, const float* __restrict__ bl1,
    const float* __restrict__ Wr1, const float* __restrict__ Wl2,
    const float* __restrict__ Wr2, float* __restrict__ comp) {
    int t = threadIdx.x;
    int m = t >> 6;          // 0:Mp 1:Np 2:Mq 3:Nq
    int k = t & 63;
    const float* W1 = (m == 0 || m == 2) ? Wl1 : Wr1;
    const float* W2 = (m < 2) ? Wl2 : Wr2;
    float a0 = 0.f, a1 = 0.f;
    for (int o = 0; o < NF; ++o) {
        float w1 = W1[o * NF + k];
        a0 = fmaf(W2[o], w1, a0);
        a1 = fmaf(W2[NF + o], w1, a1);
    }
    comp[2 * t] = a0;
    comp[2 * t + 1] = a1;
    if (t < 4) {
        const float* W2c = (t < 2) ? Wl2 : Wr2;
        int c = t & 1;
        float s = 0.f;
        for (int o = 0; o < NF; ++o) s = fmaf(bl1[o], W2c[c * NF + o], s);
        comp[512 + t] = s;
    }
}

// ---------------------------------------------------------------------------
// Gather-sum bf16 x rows over CSR + 8-FMA composite epilogue -> p,q.
// One wave per node (grid-stride); wave-uniform indices via readfirstlane;
// unroll x8 for MLP. Self term from fp32 x.
// ---------------------------------------------------------------------------
__global__ __launch_bounds__(256) void k_gatherp(
    const float* __restrict__ x,
    const unsigned short* __restrict__ xh,
    const int* __restrict__ sorted,
    const int* __restrict__ base,
    const int* __restrict__ deg,
    const float* __restrict__ comp,
    float2* __restrict__ p,
    float2* __restrict__ q,
    int N, int nwaves) {
    int tid = blockIdx.x * 256 + threadIdx.x;
    int gw = tid >> 6;
    int lane = tid & 63;

    const float2* c2 = (const float2*)comp;
    float2 mp = c2[lane];
    float2 np = c2[64 + lane];
    float2 mq = c2[128 + lane];
    float2 nq = c2[192 + lane];
    float cp0 = comp[512], cp1 = comp[513], cq0 = comp[514], cq1 = comp[515];

    for (int node = gw; node < N; node += nwaves) {
        int b0 = __builtin_amdgcn_readfirstlane(base[node]);
        int dg = __builtin_amdgcn_readfirstlane(deg[node]);

        float sum = 0.f;
        int j = 0;
        for (; j + 8 <= dg; j += 8) {
            int i0 = __builtin_amdgcn_readfirstlane(sorted[b0 + j + 0]);
            int i1 = __builtin_amdgcn_readfirstlane(sorted[b0 + j + 1]);
            int i2 = __builtin_amdgcn_readfirstlane(sorted[b0 + j + 2]);
            int i3 = __builtin_amdgcn_readfirstlane(sorted[b0 + j + 3]);
            int i4 = __builtin_amdgcn_readfirstlane(sorted[b0 + j + 4]);
            int i5 = __builtin_amdgcn_readfirstlane(sorted[b0 + j + 5]);
            int i6 = __builtin_amdgcn_readfirstlane(sorted[b0 + j + 6]);
            int i7 = __builtin_amdgcn_readfirstlane(sorted[b0 + j + 7]);
            float v0 = __uint_as_float((unsigned)xh[(size_t)i0 * NF + lane] << 16);
            float v1 = __uint_as_float((unsigned)xh[(size_t)i1 * NF + lane] << 16);
            float v2 = __uint_as_float((unsigned)xh[(size_t)i2 * NF + lane] << 16);
            float v3 = __uint_as_float((unsigned)xh[(size_t)i3 * NF + lane] << 16);
            float v4 = __uint_as_float((unsigned)xh[(size_t)i4 * NF + lane] << 16);
            float v5 = __uint_as_float((unsigned)xh[(size_t)i5 * NF + lane] << 16);
            float v6 = __uint_as_float((unsigned)xh[(size_t)i6 * NF + lane] << 16);
            float v7 = __uint_as_float((unsigned)xh[(size_t)i7 * NF + lane] << 16);
            sum += ((v0 + v1) + (v2 + v3)) + ((v4 + v5) + (v6 + v7));
        }
        for (; j < dg; ++j) {
            int i0 = __builtin_amdgcn_readfirstlane(sorted[b0 + j]);
            sum += __uint_as_float((unsigned)xh[(size_t)i0 * NF + lane] << 16);
        }
        float dgf = (float)(dg > 1 ? dg : 1);
        float mean = sum / dgf;
        float xv = x[(size_t)node * NF + lane];       // self term in fp32

        float p0 = fmaf(mean, mp.x, xv * np.x);
        float p1 = fmaf(mean, mp.y, xv * np.y);
        float q0 = fmaf(mean, mq.x, xv * nq.x);
        float q1 = fmaf(mean, mq.y, xv * nq.y);
#pragma unroll
        for (int off = 32; off > 0; off >>= 1) {
            p0 += __shfl_xor(p0, off, 64);
            p1 += __shfl_xor(p1, off, 64);
            q0 += __shfl_xor(q0, off, 64);
            q1 += __shfl_xor(q1, off, 64);
        }
        if (lane == 0) {
            p[node] = make_float2(p0 + cp0, p1 + cp1);
            q[node] = make_float2(q0 + cq0, q1 + cq1);
        }
    }
}

// ---------------------------------------------------------------------------
// Final: agg2 = gather-sum p over CSR; logits = agg2/deg + bl2 + q;
// out = log_softmax(logits). One wave per node.
// ---------------------------------------------------------------------------
__global__ __launch_bounds__(256) void k_final(
    const float2* __restrict__ p,
    const float2* __restrict__ q,
    const int* __restrict__ sorted,
    const int* __restrict__ base,
    const int* __restrict__ deg,
    const float* __restrict__ bl2,
    float* __restrict__ out,
    int N) {
    int tid = blockIdx.x * 256 + threadIdx.x;
    int node = tid >> 6;
    int lane = tid & 63;
    if (node >= N) return;
    int b0 = base[node];
    int dg = deg[node];
    float s0 = 0.f, s1 = 0.f;
    for (int j = lane; j < dg; j += 64) {
        int idx = sorted[b0 + j];
        float2 pv = p[idx];
        s0 += pv.x; s1 += pv.y;
    }
#pragma unroll
    for (int off = 32; off > 0; off >>= 1) {
        s0 += __shfl_xor(s0, off, 64);
        s1 += __shfl_xor(s1, off, 64);
    }
    if (lane == 0) {
        float dgf = (float)(dg > 1 ? dg : 1);
        float2 qv = q[node];
        float l0 = s0 / dgf + bl2[0] + qv.x;
        float l1 = s1 / dgf + bl2[1] + qv.y;
        float m = fmaxf(l0, l1);
        float lse = m + logf(expf(l0 - m) + expf(l1 - m));
        ((float2*)out)[node] = make_float2(l0 - lse, l1 - lse);
    }
}

// ---------------------------------------------------------------------------
extern "C" void kernel_launch(void* const* d_in, const int* in_sizes, int n_in,
                              void* d_out, int out_size, void* d_ws, size_t ws_size,
                              hipStream_t stream) {
    const float* x   = (const float*)d_in[0];
    const int*   ei  = (const int*)d_in[1];
    const float* Wl1 = (const float*)d_in[2];
    const float* bl1 = (const float*)d_in[3];
    const float* Wr1 = (const float*)d_in[4];
    const float* Wl2 = (const float*)d_in[5];
    const float* bl2 = (const float*)d_in[6];
    const float* Wr2 = (const float*)d_in[7];
    float* out = (float*)d_out;

    int N = in_sizes[0] / NF;     // 100000  (< 2^17 required by packing)
    int E = in_sizes[1] / 2;      // 1600000
    int nb = (N + BSZ - 1) >> SHIFT;   // 196 buckets

    // Workspace (ints): [ebin:E | sorted:E | deg:N | base:N | bhist:MAXNB |
    //                    bbase:MAXNB+1 | bcur:MAXNB]
    // then floats: [comp:516 | p:2N | q:2N] then ushorts: [xh: N*NF]
    int* wsi    = (int*)d_ws;
    int* ebin   = wsi;
    int* sorted = wsi + E;
    int* deg    = wsi + 2 * (size_t)E;
    int* base   = deg + N;
    int* bhist  = base + N;
    int* bbase  = bhist + MAXNB;
    int* bcur   = bbase + MAXNB + 1;
    float* comp = (float*)(bcur + MAXNB);
    float2* p   = (float2*)(comp + 516);
    float2* q   = p + N;
    unsigned short* xh = (unsigned short*)(q + N);

    // Zero only the bucket histogram (everything else is fully overwritten).
    hipMemsetAsync(bhist, 0, MAXNB * sizeof(int), stream);

    kb_hist<<<256, 256, 0, stream>>>(ei, bhist, E, nb);
    kb_scan<<<1, 256, 0, stream>>>(bhist, bbase, bcur, nb);
    kb_bin <<<(E + CHUNK - 1) / CHUNK, 256, 0, stream>>>(ei, bcur, ebin, E, nb);
    kb_sort<<<nb, 512, 0, stream>>>(ebin, bbase, sorted, deg, base, N, nb);

    k_compose<<<1, 256, 0, stream>>>(Wl1, bl1, Wr1, Wl2, Wr2, comp);
    k_xcast<<<1024, 256, 0, stream>>>((const float4*)x, (ushort4*)xh,
                                      N * NF / 4);

    int gblocks = 4096;                        // 16384 waves, grid-stride
    k_gatherp<<<gblocks, 256, 0, stream>>>(x, xh, sorted, base, deg, comp,
                                           p, q, N, gblocks * 4);
    k_final<<<(N * 64 + 255) / 256, 256, 0, stream>>>(p, q, sorted, base, deg,
                                                      bl2, out, N);
}